// Round 5
// baseline (147.822 us; speedup 1.0000x reference)
//
#include <hip/hip_runtime.h>
#include <hip/hip_cooperative_groups.h>

namespace cg = cooperative_groups;

#define B_DIM 32
#define T_DIM 4096
#define D_DIM 512
#define E_DIM 512
#define EPS_K 1e-7f

// ===========================================================================
// Cooperative fused kernel: yp -> sync -> scores+partials -> sync -> norm.
// All phases grid-stride (correct for any grid size); fixed-order reductions
// (deterministic, no float atomics).
// ===========================================================================
__global__ __launch_bounds__(256, 4) void fused_kernel(
    const float* __restrict__ x, const float* __restrict__ y,
    const float* __restrict__ W, const float* __restrict__ bias,
    const int* __restrict__ mask, float* __restrict__ out,
    float* __restrict__ yp, float* __restrict__ a_raw,
    float* __restrict__ partials) {

    const int wave = threadIdx.x >> 6;
    const int lane = threadIdx.x & 63;
    const int nblk = gridDim.x;
    __shared__ float ls[4];
    __shared__ float inv_s;
    cg::grid_group grid = cg::this_grid();

    // ---- Phase 0: yp[b,d] = dot(W[d,:], y[b,:]); 4096 wave-tasks x 4 d ----
    for (int gw = blockIdx.x * 4 + wave; gw < 4096; gw += nblk * 4) {
        const int idx0 = gw * 4;
        const int b0   = idx0 >> 9;
        const int d0   = idx0 & 511;
        const float4* yv = (const float4*)(y + (size_t)b0 * E_DIM);
        const float4 y0 = yv[lane];
        const float4 y1 = yv[lane + 64];
        float acc[4];
#pragma unroll
        for (int k = 0; k < 4; ++k) {
            const float4* Wv = (const float4*)(W + (size_t)(d0 + k) * E_DIM);
            const float4 w0 = Wv[lane];
            const float4 w1 = Wv[lane + 64];
            acc[k] = w0.x*y0.x + w0.y*y0.y + w0.z*y0.z + w0.w*y0.w
                   + w1.x*y1.x + w1.y*y1.y + w1.z*y1.z + w1.w*y1.w;
        }
#pragma unroll
        for (int off = 32; off > 0; off >>= 1) {
#pragma unroll
            for (int k = 0; k < 4; ++k) acc[k] += __shfl_xor(acc[k], off);
        }
        if (lane == 0)
            *(float4*)(yp + idx0) = make_float4(acc[0], acc[1], acc[2], acc[3]);
    }

    grid.sync();

    // ---- Phase 1: 1024 tasks, each = 128 consecutive t of one batch ----
    for (int task = blockIdx.x; task < 1024; task += nblk) {
        const int b     = task >> 5;
        const int tbase = (task & 31) * 128;
        const float4* ypv = (const float4*)(yp + (size_t)b * D_DIM);
        const float4 w0 = ypv[lane];
        const float4 w1 = ypv[lane + 64];
        const float bv = bias[0];
        float bsum = 0.f;

#pragma unroll
        for (int i = 0; i < 4; ++i) {
            const int t0 = tbase + wave * 32 + i * 8;
            const float4* xv = (const float4*)(x + ((size_t)b * T_DIM + t0) * D_DIM);
            float4 xa[8], xb[8];
#pragma unroll
            for (int j = 0; j < 8; ++j) {
                xa[j] = xv[j * (D_DIM / 4) + lane];
                xb[j] = xv[j * (D_DIM / 4) + lane + 64];
            }
            float p[8];
#pragma unroll
            for (int j = 0; j < 8; ++j) {
                p[j] = xa[j].x*w0.x + xa[j].y*w0.y + xa[j].z*w0.z + xa[j].w*w0.w
                     + xb[j].x*w1.x + xb[j].y*w1.y + xb[j].z*w1.z + xb[j].w*w1.w;
            }
#pragma unroll
            for (int off = 32; off > 0; off >>= 1) {
#pragma unroll
                for (int j = 0; j < 8; ++j) p[j] += __shfl_xor(p[j], off);
            }
            float a = 0.f;
            if (lane < 8) {
                float s = (lane==0)?p[0]:(lane==1)?p[1]:(lane==2)?p[2]:(lane==3)?p[3]
                        :(lane==4)?p[4]:(lane==5)?p[5]:(lane==6)?p[6]:p[7];
                const int t = t0 + lane;
                const float e = expf(tanhf(s + bv));
                a = mask[(size_t)b * T_DIM + t] ? e : 0.f;
                a_raw[(size_t)b * T_DIM + t] = a;
            }
            bsum += a;
        }

#pragma unroll
        for (int off = 32; off > 0; off >>= 1) bsum += __shfl_xor(bsum, off);
        if (lane == 0) ls[wave] = bsum;
        __syncthreads();
        if (threadIdx.x == 0)
            partials[task] = (ls[0] + ls[1]) + (ls[2] + ls[3]);
        __syncthreads();  // ls reuse across grid-stride iterations
    }

    grid.sync();

    // ---- Phase 2: 128 tasks, each normalizes 1024 floats of one batch ----
    for (int task = blockIdx.x; task < 128; task += nblk) {
        const int b = task >> 2;
        if (threadIdx.x < 32) {
            float s = partials[b * 32 + threadIdx.x];
#pragma unroll
            for (int off = 16; off > 0; off >>= 1) s += __shfl_xor(s, off);
            if (threadIdx.x == 0) inv_s = 1.0f / (s + EPS_K);
        }
        __syncthreads();
        const float inv = inv_s;
        const int idx = (task & 3) * 256 + threadIdx.x;  // float4 idx in row
        const float4 v = ((const float4*)(a_raw + (size_t)b * T_DIM))[idx];
        ((float4*)(out + (size_t)b * T_DIM))[idx] =
            make_float4(v.x * inv, v.y * inv, v.z * inv, v.w * inv);
        __syncthreads();  // inv_s reuse across grid-stride iterations
    }
}

// ===========================================================================
// Fallback path (proven R2 structure) — used if cooperative launch fails.
// ===========================================================================
__global__ __launch_bounds__(256) void yp_kernel(const float* __restrict__ y,
                                                 const float* __restrict__ W,
                                                 float* __restrict__ yp) {
    const int b    = blockIdx.y;
    const int wave = threadIdx.x >> 6;
    const int lane = threadIdx.x & 63;
    const int d    = blockIdx.x * 4 + wave;
    const float4* Wv = (const float4*)(W + (size_t)d * E_DIM);
    const float4* yv = (const float4*)(y + (size_t)b * E_DIM);
    const float4 w0 = Wv[lane];
    const float4 w1 = Wv[lane + 64];
    const float4 y0 = yv[lane];
    const float4 y1 = yv[lane + 64];
    float p = w0.x*y0.x + w0.y*y0.y + w0.z*y0.z + w0.w*y0.w
            + w1.x*y1.x + w1.y*y1.y + w1.z*y1.z + w1.w*y1.w;
#pragma unroll
    for (int off = 32; off > 0; off >>= 1) p += __shfl_xor(p, off);
    if (lane == 0) yp[(size_t)b * D_DIM + d] = p;
}

__global__ __launch_bounds__(256) void score_kernel(const float* __restrict__ x,
                                                    const float* __restrict__ yp,
                                                    const float* __restrict__ bias,
                                                    const int* __restrict__ mask,
                                                    float* __restrict__ a_raw) {
    const int b    = blockIdx.y;
    const int wave = threadIdx.x >> 6;
    const int lane = threadIdx.x & 63;
    const int t0   = blockIdx.x * 32 + wave * 8;
    const float4* ypv = (const float4*)(yp + (size_t)b * D_DIM);
    const float4 w0 = ypv[lane];
    const float4 w1 = ypv[lane + 64];
    const float4* xv = (const float4*)(x + ((size_t)b * T_DIM + (size_t)t0) * D_DIM);
    float4 xa[8], xb[8];
#pragma unroll
    for (int i = 0; i < 8; ++i) {
        xa[i] = xv[i * (D_DIM / 4) + lane];
        xb[i] = xv[i * (D_DIM / 4) + lane + 64];
    }
    float p[8];
#pragma unroll
    for (int i = 0; i < 8; ++i) {
        p[i] = xa[i].x*w0.x + xa[i].y*w0.y + xa[i].z*w0.z + xa[i].w*w0.w
             + xb[i].x*w1.x + xb[i].y*w1.y + xb[i].z*w1.z + xb[i].w*w1.w;
    }
#pragma unroll
    for (int off = 32; off > 0; off >>= 1) {
#pragma unroll
        for (int i = 0; i < 8; ++i) p[i] += __shfl_xor(p[i], off);
    }
    if (lane < 8) {
        float s = (lane==0)?p[0]:(lane==1)?p[1]:(lane==2)?p[2]:(lane==3)?p[3]
                :(lane==4)?p[4]:(lane==5)?p[5]:(lane==6)?p[6]:p[7];
        const int t = t0 + lane;
        const float e = expf(tanhf(s + bias[0]));
        a_raw[(size_t)b * T_DIM + t] = mask[(size_t)b * T_DIM + t] ? e : 0.f;
    }
}

__global__ __launch_bounds__(1024) void norm_kernel(const float* __restrict__ a_raw,
                                                    float* __restrict__ out) {
    const int b   = blockIdx.x;
    const int tid = threadIdx.x;
    const float4 v = ((const float4*)(a_raw + (size_t)b * T_DIM))[tid];
    float s = v.x + v.y + v.z + v.w;
#pragma unroll
    for (int off = 32; off > 0; off >>= 1) s += __shfl_xor(s, off);
    __shared__ float wsum[16];
    __shared__ float inv_s;
    if ((tid & 63) == 0) wsum[tid >> 6] = s;
    __syncthreads();
    if (tid == 0) {
        float tot = 0.f;
        for (int i = 0; i < 16; ++i) tot += wsum[i];
        inv_s = 1.0f / (tot + EPS_K);
    }
    __syncthreads();
    const float inv = inv_s;
    ((float4*)(out + (size_t)b * T_DIM))[tid] =
        make_float4(v.x * inv, v.y * inv, v.z * inv, v.w * inv);
}

// ===========================================================================
extern "C" void kernel_launch(void* const* d_in, const int* in_sizes, int n_in,
                              void* d_out, int out_size, void* d_ws, size_t ws_size,
                              hipStream_t stream) {
    const float* x    = (const float*)d_in[0];  // [B,T,D]
    const float* y    = (const float*)d_in[1];  // [B,E]
    const float* W    = (const float*)d_in[2];  // [D,E]
    const float* bias = (const float*)d_in[3];  // [1]
    const int*   mask = (const int*)d_in[4];    // [B,T]
    float* out = (float*)d_out;                 // [B,T]

    float* yp       = (float*)d_ws;             // 64 KB
    float* a_raw    = yp + B_DIM * D_DIM;       // 512 KB
    float* partials = a_raw + B_DIM * T_DIM;    // 4 KB

    // Size the cooperative grid from measured occupancy; grid-stride makes
    // any size correct. Fall back to the 3-kernel path on any failure.
    int occ = 0;
    hipError_t oe = hipOccupancyMaxActiveBlocksPerMultiprocessor(&occ, fused_kernel, 256, 0);
    if (oe == hipSuccess && occ >= 1) {
        int nblk = occ * 256;                   // 256 CUs on MI355X
        if (nblk > 1024) nblk = 1024;
        void* args[] = {(void*)&x, (void*)&y, (void*)&W, (void*)&bias,
                        (void*)&mask, (void*)&out, (void*)&yp, (void*)&a_raw,
                        (void*)&partials};
        hipError_t le = hipLaunchCooperativeKernel(fused_kernel, dim3(nblk),
                                                   dim3(256), args, 0u, stream);
        if (le == hipSuccess) return;
    }

    yp_kernel<<<dim3(D_DIM / 4, B_DIM), 256, 0, stream>>>(y, W, yp);
    score_kernel<<<dim3(T_DIM / 32, B_DIM), 256, 0, stream>>>(x, yp, bias, mask, a_raw);
    norm_kernel<<<B_DIM, 1024, 0, stream>>>(a_raw, out);
}

// Round 6
// 50.869 us; speedup vs baseline: 2.9060x; 2.9060x over previous
//
#include <hip/hip_runtime.h>
#include <hip/hip_cooperative_groups.h>

namespace cg = cooperative_groups;

#define B_DIM 32
#define T_DIM 4096
#define D_DIM 512
#define E_DIM 512
#define EPS_K 1e-7f
#define NBLK 1024   // exactly 4 blocks/CU x 256 CU; every phase indexes off blockIdx

// ===========================================================================
// Cooperative fused kernel, straight-line phases (no grid-stride wrappers):
//   P0: yp = y @ W^T          (4096 waves x 4 rows)
//   P1: scores + block partials (1024 blocks x 128 t, R2's proven body)
//   P2: redundant partial-reduce + normalize + store
// Fixed-order reductions only (deterministic).
// ===========================================================================
__global__ __launch_bounds__(256) void fused_kernel(
    const float* __restrict__ x, const float* __restrict__ y,
    const float* __restrict__ W, const float* __restrict__ bias,
    const int* __restrict__ mask, float* __restrict__ out,
    float* __restrict__ yp, float* __restrict__ a_raw,
    float* __restrict__ partials) {

    const int bid  = blockIdx.x;
    const int wave = threadIdx.x >> 6;
    const int lane = threadIdx.x & 63;
    __shared__ float ls[4];
    __shared__ float inv_s;
    cg::grid_group grid = cg::this_grid();

    // ---- Phase 0: yp[b,d] = dot(W[d,:], y[b,:]); wave gw does 4 rows ----
    {
        const int gw   = bid * 4 + wave;   // 0..4095
        const int idx0 = gw * 4;           // 4 consecutive (b,d), same b
        const int b0   = idx0 >> 9;
        const int d0   = idx0 & 511;
        const float4* yv = (const float4*)(y + (size_t)b0 * E_DIM);
        const float4 y0 = yv[lane];
        const float4 y1 = yv[lane + 64];
        float acc[4];
#pragma unroll
        for (int k = 0; k < 4; ++k) {
            const float4* Wv = (const float4*)(W + (size_t)(d0 + k) * E_DIM);
            const float4 w0 = Wv[lane];
            const float4 w1 = Wv[lane + 64];
            acc[k] = w0.x*y0.x + w0.y*y0.y + w0.z*y0.z + w0.w*y0.w
                   + w1.x*y1.x + w1.y*y1.y + w1.z*y1.z + w1.w*y1.w;
        }
#pragma unroll
        for (int off = 32; off > 0; off >>= 1) {
#pragma unroll
            for (int k = 0; k < 4; ++k) acc[k] += __shfl_xor(acc[k], off);
        }
        if (lane == 0)
            *(float4*)(yp + idx0) = make_float4(acc[0], acc[1], acc[2], acc[3]);
    }

    grid.sync();

    // ---- Phase 1: block bid owns 128 consecutive t of batch b ----
    const int b     = bid >> 5;            // 32 blocks per batch
    const int tbase = (bid & 31) * 128;
    {
        const float4* ypv = (const float4*)(yp + (size_t)b * D_DIM);
        const float4 w0 = ypv[lane];
        const float4 w1 = ypv[lane + 64];
        const float bv = bias[0];
        float bsum = 0.f;

#pragma unroll
        for (int i = 0; i < 4; ++i) {
            const int t0 = tbase + wave * 32 + i * 8;
            const float4* xv = (const float4*)(x + ((size_t)b * T_DIM + t0) * D_DIM);
            float4 xa[8], xb[8];
#pragma unroll
            for (int j = 0; j < 8; ++j) {
                xa[j] = xv[j * (D_DIM / 4) + lane];
                xb[j] = xv[j * (D_DIM / 4) + lane + 64];
            }
            float p[8];
#pragma unroll
            for (int j = 0; j < 8; ++j) {
                p[j] = xa[j].x*w0.x + xa[j].y*w0.y + xa[j].z*w0.z + xa[j].w*w0.w
                     + xb[j].x*w1.x + xb[j].y*w1.y + xb[j].z*w1.z + xb[j].w*w1.w;
            }
#pragma unroll
            for (int off = 32; off > 0; off >>= 1) {
#pragma unroll
                for (int j = 0; j < 8; ++j) p[j] += __shfl_xor(p[j], off);
            }
            float a = 0.f;
            if (lane < 8) {
                float s = (lane==0)?p[0]:(lane==1)?p[1]:(lane==2)?p[2]:(lane==3)?p[3]
                        :(lane==4)?p[4]:(lane==5)?p[5]:(lane==6)?p[6]:p[7];
                const int t = t0 + lane;
                const float e = expf(tanhf(s + bv));
                a = mask[(size_t)b * T_DIM + t] ? e : 0.f;
                a_raw[(size_t)b * T_DIM + t] = a;
            }
            bsum += a;
        }

#pragma unroll
        for (int off = 32; off > 0; off >>= 1) bsum += __shfl_xor(bsum, off);
        if (lane == 0) ls[wave] = bsum;
        __syncthreads();
        if (threadIdx.x == 0)
            partials[bid] = (ls[0] + ls[1]) + (ls[2] + ls[3]);
    }

    grid.sync();

    // ---- Phase 2: block bid normalizes its own 128 t's ----
    if (threadIdx.x < 32) {
        float s = partials[b * 32 + threadIdx.x];
#pragma unroll
        for (int off = 16; off > 0; off >>= 1) s += __shfl_xor(s, off);
        if (threadIdx.x == 0) inv_s = 1.0f / (s + EPS_K);
    }
    __syncthreads();
    const float inv = inv_s;
    if (threadIdx.x < 32) {
        const int idx = (bid & 31) * 32 + threadIdx.x;   // float4 index in row
        const float4 v = ((const float4*)(a_raw + (size_t)b * T_DIM))[idx];
        ((float4*)(out + (size_t)b * T_DIM))[idx] =
            make_float4(v.x * inv, v.y * inv, v.z * inv, v.w * inv);
    }
}

// ===========================================================================
// Fallback path (proven R2 structure) — used if cooperative launch fails.
// ===========================================================================
__global__ __launch_bounds__(256) void yp_kernel(const float* __restrict__ y,
                                                 const float* __restrict__ W,
                                                 float* __restrict__ yp) {
    const int b    = blockIdx.y;
    const int wave = threadIdx.x >> 6;
    const int lane = threadIdx.x & 63;
    const int d    = blockIdx.x * 4 + wave;
    const float4* Wv = (const float4*)(W + (size_t)d * E_DIM);
    const float4* yv = (const float4*)(y + (size_t)b * E_DIM);
    const float4 w0 = Wv[lane];
    const float4 w1 = Wv[lane + 64];
    const float4 y0 = yv[lane];
    const float4 y1 = yv[lane + 64];
    float p = w0.x*y0.x + w0.y*y0.y + w0.z*y0.z + w0.w*y0.w
            + w1.x*y1.x + w1.y*y1.y + w1.z*y1.z + w1.w*y1.w;
#pragma unroll
    for (int off = 32; off > 0; off >>= 1) p += __shfl_xor(p, off);
    if (lane == 0) yp[(size_t)b * D_DIM + d] = p;
}

__global__ __launch_bounds__(256) void score_kernel(const float* __restrict__ x,
                                                    const float* __restrict__ yp,
                                                    const float* __restrict__ bias,
                                                    const int* __restrict__ mask,
                                                    float* __restrict__ a_raw) {
    const int b    = blockIdx.y;
    const int wave = threadIdx.x >> 6;
    const int lane = threadIdx.x & 63;
    const int t0   = blockIdx.x * 32 + wave * 8;
    const float4* ypv = (const float4*)(yp + (size_t)b * D_DIM);
    const float4 w0 = ypv[lane];
    const float4 w1 = ypv[lane + 64];
    const float4* xv = (const float4*)(x + ((size_t)b * T_DIM + (size_t)t0) * D_DIM);
    float4 xa[8], xb[8];
#pragma unroll
    for (int i = 0; i < 8; ++i) {
        xa[i] = xv[i * (D_DIM / 4) + lane];
        xb[i] = xv[i * (D_DIM / 4) + lane + 64];
    }
    float p[8];
#pragma unroll
    for (int i = 0; i < 8; ++i) {
        p[i] = xa[i].x*w0.x + xa[i].y*w0.y + xa[i].z*w0.z + xa[i].w*w0.w
             + xb[i].x*w1.x + xb[i].y*w1.y + xb[i].z*w1.z + xb[i].w*w1.w;
    }
#pragma unroll
    for (int off = 32; off > 0; off >>= 1) {
#pragma unroll
        for (int i = 0; i < 8; ++i) p[i] += __shfl_xor(p[i], off);
    }
    if (lane < 8) {
        float s = (lane==0)?p[0]:(lane==1)?p[1]:(lane==2)?p[2]:(lane==3)?p[3]
                :(lane==4)?p[4]:(lane==5)?p[5]:(lane==6)?p[6]:p[7];
        const int t = t0 + lane;
        const float e = expf(tanhf(s + bias[0]));
        a_raw[(size_t)b * T_DIM + t] = mask[(size_t)b * T_DIM + t] ? e : 0.f;
    }
}

__global__ __launch_bounds__(1024) void norm_kernel(const float* __restrict__ a_raw,
                                                    float* __restrict__ out) {
    const int b   = blockIdx.x;
    const int tid = threadIdx.x;
    const float4 v = ((const float4*)(a_raw + (size_t)b * T_DIM))[tid];
    float s = v.x + v.y + v.z + v.w;
#pragma unroll
    for (int off = 32; off > 0; off >>= 1) s += __shfl_xor(s, off);
    __shared__ float wsum[16];
    __shared__ float inv_s;
    if ((tid & 63) == 0) wsum[tid >> 6] = s;
    __syncthreads();
    if (tid == 0) {
        float tot = 0.f;
        for (int i = 0; i < 16; ++i) tot += wsum[i];
        inv_s = 1.0f / (tot + EPS_K);
    }
    __syncthreads();
    const float inv = inv_s;
    ((float4*)(out + (size_t)b * T_DIM))[tid] =
        make_float4(v.x * inv, v.y * inv, v.z * inv, v.w * inv);
}

// ===========================================================================
extern "C" void kernel_launch(void* const* d_in, const int* in_sizes, int n_in,
                              void* d_out, int out_size, void* d_ws, size_t ws_size,
                              hipStream_t stream) {
    const float* x    = (const float*)d_in[0];  // [B,T,D]
    const float* y    = (const float*)d_in[1];  // [B,E]
    const float* W    = (const float*)d_in[2];  // [D,E]
    const float* bias = (const float*)d_in[3];  // [1]
    const int*   mask = (const int*)d_in[4];    // [B,T]
    float* out = (float*)d_out;                 // [B,T]

    float* yp       = (float*)d_ws;             // 64 KB
    float* a_raw    = yp + B_DIM * D_DIM;       // 512 KB
    float* partials = a_raw + B_DIM * T_DIM;    // 4 KB

    // Cooperative path requires >=4 co-resident blocks/CU (grid is exactly
    // NBLK=1024 and the kernel indexes off blockIdx). Otherwise fallback.
    int occ = 0;
    hipError_t oe = hipOccupancyMaxActiveBlocksPerMultiprocessor(&occ, fused_kernel, 256, 0);
    if (oe == hipSuccess && occ >= 4) {
        void* args[] = {(void*)&x, (void*)&y, (void*)&W, (void*)&bias,
                        (void*)&mask, (void*)&out, (void*)&yp, (void*)&a_raw,
                        (void*)&partials};
        hipError_t le = hipLaunchCooperativeKernel(fused_kernel, dim3(NBLK),
                                                   dim3(256), args, 0u, stream);
        if (le == hipSuccess) return;
    }

    yp_kernel<<<dim3(D_DIM / 4, B_DIM), 256, 0, stream>>>(y, W, yp);
    score_kernel<<<dim3(T_DIM / 32, B_DIM), 256, 0, stream>>>(x, yp, bias, mask, a_raw);
    norm_kernel<<<B_DIM, 1024, 0, stream>>>(a_raw, out);
}